// Round 2
// baseline (395.768 us; speedup 1.0000x reference)
//
#include <hip/hip_runtime.h>

#define B_ 16
#define D_ 128
#define L_ 8192
#define M_ 128
#define NCA 32        // kernelA chunks over L
#define LTA 256       // l per A-block
#define NCC 64        // kernelC chunks over L
#define LTC 128       // l per C-block
#define SL 64
#define PHI_SCALE 0.08838834764831845f

typedef unsigned short ushort_t;
typedef ushort_t ushort8 __attribute__((ext_vector_type(8)));
typedef ushort_t ushort4v __attribute__((ext_vector_type(4)));
typedef float float4v __attribute__((ext_vector_type(4)));
typedef __bf16 bf16x8 __attribute__((ext_vector_type(8)));

__device__ __forceinline__ ushort_t f2bf(float f) {
    unsigned int u = __builtin_bit_cast(unsigned int, f);
    unsigned int r = u + 0x7FFFu + ((u >> 16) & 1u);   // RTNE
    return (ushort_t)(r >> 16);
}

__device__ __forceinline__ float4v mfma16(ushort8 a, ushort8 b, float4v c) {
    return __builtin_amdgcn_mfma_f32_16x16x32_bf16(
        __builtin_bit_cast(bf16x8, a), __builtin_bit_cast(bf16x8, b), c, 0, 0, 0);
}

// ---- kernelF: features (D x M fp32) -> bf16 B-frag array in global.
// slot bid = (kt*8+nt)*64 + lane; lane=qb*16+cb -> k d = kt*32+qb*8+j, n m = nt*16+cb
__global__ __launch_bounds__(256) void kernelF(const float* __restrict__ features,
                                               ushort_t* __restrict__ Ffrag) {
    int bid = blockIdx.x * 256 + threadIdx.x;  // 0..2047
    int cb = bid & 15, qb = (bid >> 4) & 3, nt = (bid >> 6) & 7, kt = bid >> 9;
    int m = nt * 16 + cb;
    int d0 = kt * 32 + qb * 8;
    const float* fp = features + d0 * M_ + m;
    ushort8 u;
#pragma unroll
    for (int j = 0; j < 8; ++j) u[j] = f2bf(fp[j * M_]);
    *(ushort8*)(Ffrag + bid * 8) = u;
}

// Stage F into LDS as B-frag layout (kernelA only)
__device__ __forceinline__ void stage_features(const float* __restrict__ features,
                                               ushort_t* FB, int tid) {
#pragma unroll
    for (int it = 0; it < 8; ++it) {
        int bid = tid + it * 256;
        int cb = bid & 15;
        int qb = (bid >> 4) & 3;
        int nt = (bid >> 6) & 7;
        int kt = bid >> 9;
        int m  = nt * 16 + cb;
        int d0 = kt * 32 + qb * 8;
        const float* fp = features + d0 * M_ + m;
        ushort8 u;
#pragma unroll
        for (int j = 0; j < 8; ++j) u[j] = f2bf(fp[j * M_]);
        *(ushort8*)(FB + bid * 8) = u;
    }
}

// ---- kernelA: per (chunk,b): phi_k = relu(K^T F)*s ; kv_part += phi^T V^T ; ksum partials
__global__ __launch_bounds__(256) void kernelA(const float* __restrict__ keys,
                                               const float* __restrict__ values,
                                               const float* __restrict__ features,
                                               float* __restrict__ kvp,
                                               float* __restrict__ ksum_p) {
    __shared__ ushort_t FB[16384];  // 32 KB
    __shared__ ushort_t PA[8192];   // 16 KB
    __shared__ ushort_t VB[8192];   // 16 KB

    const int tid = threadIdx.x;
    const int chunk = blockIdx.x, b = blockIdx.y;
    const int w = tid >> 6, lane = tid & 63;
    const int qa = lane >> 4, ra = lane & 15;

    stage_features(features, FB, tid);

    float4v acc2[2][8];
    float   ksum_acc[8];
#pragma unroll
    for (int i = 0; i < 2; ++i)
#pragma unroll
        for (int nt = 0; nt < 8; ++nt) acc2[i][nt] = (float4v){0.f, 0.f, 0.f, 0.f};
#pragma unroll
    for (int nt = 0; nt < 8; ++nt) ksum_acc[nt] = 0.f;

    const int l0 = chunk * LTA;

    for (int s = 0; s < LTA / SL; ++s) {
        const int ls = l0 + s * SL;
        __syncthreads();

        // stage V subtile into B-frag layout: B[k=l_rel][n=v]
#pragma unroll
        for (int it = 0; it < 4; ++it) {
            int bid = tid + it * 256;
            int cb = bid & 15;
            int qb = (bid >> 4) & 3;
            int nt = (bid >> 6) & 7;
            int kt = bid >> 9;
            int v  = nt * 16 + cb;
            int lr = kt * 32 + qb * 8;
            const float* vp = values + ((size_t)(b * D_ + v)) * L_ + ls + lr;
            float4v f0 = *(const float4v*)vp;
            float4v f1 = *(const float4v*)(vp + 4);
            ushort8 u;
            u[0] = f2bf(f0.x); u[1] = f2bf(f0.y); u[2] = f2bf(f0.z); u[3] = f2bf(f0.w);
            u[4] = f2bf(f1.x); u[5] = f2bf(f1.y); u[6] = f2bf(f1.z); u[7] = f2bf(f1.w);
            *(ushort8*)(VB + bid * 8) = u;
        }

        // GEMM1: phi(64 x 128) = K_sub^T @ F
        float4v acc1[8];
#pragma unroll
        for (int nt = 0; nt < 8; ++nt) acc1[nt] = (float4v){0.f, 0.f, 0.f, 0.f};
        const int l = ls + w * 16 + ra;
#pragma unroll
        for (int kt = 0; kt < 4; ++kt) {
            const float* kp = keys + ((size_t)(b * D_ + kt * 32 + qa * 8)) * L_ + l;
            ushort8 a;
#pragma unroll
            for (int j = 0; j < 8; ++j) a[j] = f2bf(kp[(size_t)j * L_]);
#pragma unroll
            for (int nt = 0; nt < 8; ++nt)
                acc1[nt] = mfma16(a, *(const ushort8*)(FB + ((kt * 8 + nt) * 64 + lane) * 8),
                                  acc1[nt]);
        }

        // epilogue: relu*scale, ksum, phi^T -> A-frag layout in PA
        {
            const int qc = qa, cc = ra;
            const int kt2 = w >> 1;
            const int qa2 = (w & 1) * 2 + (qc >> 1);
            const int jb  = (qc & 1) * 4;
#pragma unroll
            for (int nt = 0; nt < 8; ++nt) {
                float4v p = acc1[nt];
                p.x = fmaxf(p.x, 0.f) * PHI_SCALE;
                p.y = fmaxf(p.y, 0.f) * PHI_SCALE;
                p.z = fmaxf(p.z, 0.f) * PHI_SCALE;
                p.w = fmaxf(p.w, 0.f) * PHI_SCALE;
                ksum_acc[nt] += p.x + p.y + p.z + p.w;
                ushort4v u4 = {f2bf(p.x), f2bf(p.y), f2bf(p.z), f2bf(p.w)};
                *(ushort4v*)(PA + (((kt2 * 8 + nt) * 64 + qa2 * 16 + cc) * 8 + jb)) = u4;
            }
        }
        __syncthreads();

        // GEMM2: kv[m][v] += phi^T (128 x 64) @ V (64 x 128)
#pragma unroll
        for (int kt2 = 0; kt2 < 2; ++kt2) {
            ushort8 a0 = *(const ushort8*)(PA + ((kt2 * 8 + 2 * w + 0) * 64 + lane) * 8);
            ushort8 a1 = *(const ushort8*)(PA + ((kt2 * 8 + 2 * w + 1) * 64 + lane) * 8);
#pragma unroll
            for (int nt = 0; nt < 8; ++nt) {
                ushort8 bb = *(const ushort8*)(VB + ((kt2 * 8 + nt) * 64 + lane) * 8);
                acc2[0][nt] = mfma16(a0, bb, acc2[0][nt]);
                acc2[1][nt] = mfma16(a1, bb, acc2[1][nt]);
            }
        }
    }

    float* kvpb = kvp + ((size_t)(b * NCA + chunk)) * M_ * D_;
    const int qc = lane >> 4, cc = lane & 15;
#pragma unroll
    for (int mi = 0; mi < 2; ++mi)
#pragma unroll
        for (int nt = 0; nt < 8; ++nt) {
            float4v p = acc2[mi][nt];
            int m0 = w * 32 + mi * 16 + qc * 4;
            int v  = nt * 16 + cc;
            kvpb[(m0 + 0) * D_ + v] = p.x;
            kvpb[(m0 + 1) * D_ + v] = p.y;
            kvpb[(m0 + 2) * D_ + v] = p.z;
            kvpb[(m0 + 3) * D_ + v] = p.w;
        }
    float* ksb = ksum_p + ((size_t)((b * NCA + chunk) * 4 + w)) * M_;
#pragma unroll
    for (int nt = 0; nt < 8; ++nt) {
        float sv = ksum_acc[nt];
        sv += __shfl_xor(sv, 16);
        sv += __shfl_xor(sv, 32);
        if (qc == 0) ksb[nt * 16 + cc] = sv;
    }
}

// ---- kernelR: reduce partials -> kv^T A-frags (bf16, global) + ksum fp32
// kvT slot (b, ktile, vt, lane): lane=qa*16+ra -> row v = vt*16+ra, k m = ktile*32+qa*8+j
__global__ __launch_bounds__(256) void kernelR(const float* __restrict__ kvp,
                                               const float* __restrict__ ksum_p,
                                               ushort_t* __restrict__ kvT,
                                               float* __restrict__ ksum_f) {
    int t = blockIdx.x * 256 + threadIdx.x;
    if (t < 32768) {
        int b = t >> 11, s = t & 2047;
        int lane = s & 63, vt = (s >> 6) & 7, ktile = s >> 9;
        int qa = lane >> 4, ra = lane & 15;
        int v = vt * 16 + ra;
        ushort8 u;
#pragma unroll
        for (int j = 0; j < 8; ++j) {
            int m = ktile * 32 + qa * 8 + j;
            float sum = 0.f;
            for (int c = 0; c < NCA; ++c)
                sum += kvp[(((size_t)(b * NCA + c)) * M_ + m) * D_ + v];
            u[j] = f2bf(sum);
        }
        *(ushort8*)(kvT + (size_t)t * 8) = u;
    } else if (t < 34816) {
        int i = t - 32768, b = i >> 7, m = i & 127;
        float sum = 0.f;
        for (int c = 0; c < NCA; ++c)
#pragma unroll
            for (int w2 = 0; w2 < 4; ++w2)
                sum += ksum_p[((size_t)((b * NCA + c) * 4 + w2)) * M_ + m];
        ksum_f[b * 128 + m] = sum;
    }
}

// ---- kernelC: fused phi_q + out. No barriers (all LDS traffic is wave-private).
// GEMM1: phi(64l x 128m) = relu(Q^T F)*s  (F B-frags from global)
// denom via VALU dot with ksum + 16-lane xor reduce
// GEMM2: out^T(128v x 64l) = kv^T(v,m) @ phi^T(m,l); kv^T A-frags from global,
//        phi^T B-frags via wave-private LDS scatter.
__global__ __launch_bounds__(256, 4) void kernelC(const float* __restrict__ queries,
                                                  const ushort_t* __restrict__ Ffrag,
                                                  const ushort_t* __restrict__ kvT,
                                                  const float* __restrict__ ksum_f,
                                                  float* __restrict__ out) {
    __shared__ ushort_t PA[8192];  // 16 KB: phi^T B-frags, 4 KB per wave
    __shared__ float DEN[64];      // per-wave 16 inverse... raw denoms

    const int tid = threadIdx.x;
    const int chunk = blockIdx.x, b = blockIdx.y;
    const int w = tid >> 6, lane = tid & 63;
    const int qa = lane >> 4, ra = lane & 15;

    float ksr[8];
#pragma unroll
    for (int nt = 0; nt < 8; ++nt) ksr[nt] = ksum_f[b * 128 + nt * 16 + ra];

    for (int s = 0; s < LTC / SL; ++s) {
        const int ls = chunk * LTC + s * SL;
        const int l = ls + w * 16 + ra;

        // GEMM1
        float4v acc1[8];
#pragma unroll
        for (int nt = 0; nt < 8; ++nt) acc1[nt] = (float4v){0.f, 0.f, 0.f, 0.f};
#pragma unroll
        for (int kt = 0; kt < 4; ++kt) {
            const float* qp = queries + ((size_t)(b * D_ + kt * 32 + qa * 8)) * L_ + l;
            ushort8 a;
#pragma unroll
            for (int j = 0; j < 8; ++j) a[j] = f2bf(qp[(size_t)j * L_]);
#pragma unroll
            for (int nt = 0; nt < 8; ++nt)
                acc1[nt] = mfma16(a, *(const ushort8*)(Ffrag + ((kt * 8 + nt) * 64 + lane) * 8),
                                  acc1[nt]);
        }

        // epilogue: relu*scale; denom dot; scatter phi^T into B-frag layout
        // value at (l = ls + w*16 + qc*4 + i, m = nt*16 + cc):
        //   B-frag slot (ktile=nt>>1, ntile=w): pos qb = (nt&1)*2+(cc>>3), cb = qc*4+i, j = cc&7
        float d0 = 0.f, d1 = 0.f, d2 = 0.f, d3 = 0.f;
        const int qc = qa, cc = ra;
#pragma unroll
        for (int nt = 0; nt < 8; ++nt) {
            float4v p = acc1[nt];
            p.x = fmaxf(p.x, 0.f) * PHI_SCALE;
            p.y = fmaxf(p.y, 0.f) * PHI_SCALE;
            p.z = fmaxf(p.z, 0.f) * PHI_SCALE;
            p.w = fmaxf(p.w, 0.f) * PHI_SCALE;
            d0 += p.x * ksr[nt];
            d1 += p.y * ksr[nt];
            d2 += p.z * ksr[nt];
            d3 += p.w * ksr[nt];
            int ktile = nt >> 1;
            int qb = (nt & 1) * 2 + (cc >> 3);
            ushort_t* pp = PA + (((ktile * 4 + w) * 64 + qb * 16 + qc * 4) * 8 + (cc & 7));
            pp[0]  = f2bf(p.x);
            pp[8]  = f2bf(p.y);
            pp[16] = f2bf(p.z);
            pp[24] = f2bf(p.w);
        }
#pragma unroll
        for (int msk = 1; msk < 16; msk <<= 1) {
            d0 += __shfl_xor(d0, msk);
            d1 += __shfl_xor(d1, msk);
            d2 += __shfl_xor(d2, msk);
            d3 += __shfl_xor(d3, msk);
        }
        if (ra == 0) *(float4v*)(DEN + w * 16 + qc * 4) = (float4v){d0, d1, d2, d3};

        // GEMM2: out^T tile (128v x 16l), wave-private
        float id_;
        {
            // RAW on DEN within wave — compiler inserts lgkmcnt wait
            id_ = 1.0f / DEN[w * 16 + ra];
        }
        float4v acc2[8];
#pragma unroll
        for (int vt = 0; vt < 8; ++vt) acc2[vt] = (float4v){0.f, 0.f, 0.f, 0.f};
#pragma unroll
        for (int ktile = 0; ktile < 4; ++ktile) {
            ushort8 bf = *(const ushort8*)(PA + ((ktile * 4 + w) * 64 + lane) * 8);
#pragma unroll
            for (int vt = 0; vt < 8; ++vt) {
                ushort8 af = *(const ushort8*)(kvT +
                    ((size_t)(b * 2048 + (ktile * 8 + vt) * 64 + lane)) * 8);
                acc2[vt] = mfma16(af, bf, acc2[vt]);
            }
        }
        // store: acc2[vt] C-layout: row v = vt*16 + qa*4 + i, col l = ls + w*16 + ra
#pragma unroll
        for (int vt = 0; vt < 8; ++vt) {
            float* op = out + ((size_t)(b * D_ + vt * 16 + qa * 4)) * L_ + ls + w * 16 + ra;
            op[0 * L_] = acc2[vt].x * id_;
            op[1 * L_] = acc2[vt].y * id_;
            op[2 * L_] = acc2[vt].z * id_;
            op[3 * L_] = acc2[vt].w * id_;
        }
    }
}

extern "C" void kernel_launch(void* const* d_in, const int* in_sizes, int n_in,
                              void* d_out, int out_size, void* d_ws, size_t ws_size,
                              hipStream_t stream) {
    (void)in_sizes; (void)n_in; (void)out_size; (void)ws_size;
    const float* keys     = (const float*)d_in[0];
    const float* values   = (const float*)d_in[1];
    const float* queries  = (const float*)d_in[2];
    const float* features = (const float*)d_in[3];
    float* out = (float*)d_out;

    // workspace partition (~35.2 MB)
    char* ws = (char*)d_ws;
    float*    kvp    = (float*)ws;                              // 16*32*128*128*4 = 33,554,432
    float*    ksum_p = (float*)(ws + 33554432);                 // 16*32*4*128*4   =  1,048,576
    ushort_t* Ffrag  = (ushort_t*)(ws + 33554432 + 1048576);    // 2048*8*2        =     32,768
    ushort_t* kvT    = (ushort_t*)(ws + 33554432 + 1048576 + 32768);        // 16*2048*8*2 = 524,288
    float*    ksum_f = (float*)(ws + 33554432 + 1048576 + 32768 + 524288);  // 16*128*4    =   8,192

    kernelF<<<8, 256, 0, stream>>>(features, Ffrag);
    kernelA<<<dim3(NCA, B_), 256, 0, stream>>>(keys, values, features, kvp, ksum_p);
    kernelR<<<136, 256, 0, stream>>>(kvp, ksum_p, kvT, ksum_f);
    kernelC<<<dim3(NCC, B_), 256, 0, stream>>>(queries, Ffrag, kvT, ksum_f, out);
}

// Round 3
// 314.397 us; speedup vs baseline: 1.2588x; 1.2588x over previous
//
#include <hip/hip_runtime.h>

#define B_ 16
#define D_ 128
#define L_ 8192
#define M_ 128
#define NCA 32        // kernelA chunks over L
#define LTA 256       // l per A-block
#define NCC 64        // kernelC chunks over L
#define LTC 128       // l per C-block
#define SL 64
#define PHI_SCALE 0.08838834764831845f

typedef unsigned short ushort_t;
typedef ushort_t ushort8 __attribute__((ext_vector_type(8)));
typedef ushort_t ushort4v __attribute__((ext_vector_type(4)));
typedef float float4v __attribute__((ext_vector_type(4)));
typedef __bf16 bf16x8 __attribute__((ext_vector_type(8)));

__device__ __forceinline__ ushort_t f2bf(float f) {
    unsigned int u = __builtin_bit_cast(unsigned int, f);
    unsigned int r = u + 0x7FFFu + ((u >> 16) & 1u);   // RTNE
    return (ushort_t)(r >> 16);
}

__device__ __forceinline__ float4v mfma16(ushort8 a, ushort8 b, float4v c) {
    return __builtin_amdgcn_mfma_f32_16x16x32_bf16(
        __builtin_bit_cast(bf16x8, a), __builtin_bit_cast(bf16x8, b), c, 0, 0, 0);
}

// ---- kernelF: features (D x M fp32) -> bf16 B-frag array in global (L2-resident).
// slot bid = (kt*8+nt)*64 + lane; lane=qb*16+cb -> k d = kt*32+qb*8+j, n m = nt*16+cb
__global__ __launch_bounds__(256) void kernelF(const float* __restrict__ features,
                                               ushort_t* __restrict__ Ffrag) {
    int bid = blockIdx.x * 256 + threadIdx.x;  // 0..2047
    int cb = bid & 15, qb = (bid >> 4) & 3, nt = (bid >> 6) & 7, kt = bid >> 9;
    int m = nt * 16 + cb;
    int d0 = kt * 32 + qb * 8;
    const float* fp = features + d0 * M_ + m;
    ushort8 u;
#pragma unroll
    for (int j = 0; j < 8; ++j) u[j] = f2bf(fp[j * M_]);
    *(ushort8*)(Ffrag + bid * 8) = u;
}

// ---- kernelA: phi_k = relu(K^T F)*s ; kv_part += phi^T V^T ; ksum partials.
// LDS: double-buffered phi A-frags only (32 KB). One barrier per 64-l iter.
// GEMM1: wave w owns l rows [w*16, w*16+16); F B-frags from global (L1-hot).
// GEMM2: wave w owns v cols [w*32, w*32+32); V B-frags direct from global (contig float4).
__global__ __launch_bounds__(256) void kernelA(const float* __restrict__ keys,
                                               const float* __restrict__ values,
                                               const ushort_t* __restrict__ Ffrag,
                                               float* __restrict__ kvp,
                                               float* __restrict__ ksum_p) {
    __shared__ ushort_t PA[2][8192];  // 2 x 16 KB phi^T A-frags

    const int tid = threadIdx.x;
    const int chunk = blockIdx.x, b = blockIdx.y;
    const int w = tid >> 6, lane = tid & 63;
    const int qa = lane >> 4, ra = lane & 15;

    float4v acc2[8][2];
    float   ksum_acc[8];
#pragma unroll
    for (int mt = 0; mt < 8; ++mt) {
        acc2[mt][0] = (float4v){0.f, 0.f, 0.f, 0.f};
        acc2[mt][1] = (float4v){0.f, 0.f, 0.f, 0.f};
        ksum_acc[mt] = 0.f;
    }

    const int l0 = chunk * LTA;

    for (int s = 0; s < LTA / SL; ++s) {
        const int ls = l0 + s * SL;

        // GEMM1: phi(64l x 128m) = K_sub^T @ F ; rows l = ls + w*16 + ra
        float4v acc1[8];
#pragma unroll
        for (int nt = 0; nt < 8; ++nt) acc1[nt] = (float4v){0.f, 0.f, 0.f, 0.f};
        const int l = ls + w * 16 + ra;
#pragma unroll
        for (int kt = 0; kt < 4; ++kt) {
            const float* kp = keys + ((size_t)(b * D_ + kt * 32 + qa * 8)) * L_ + l;
            ushort8 a;
#pragma unroll
            for (int j = 0; j < 8; ++j) a[j] = f2bf(kp[(size_t)j * L_]);
#pragma unroll
            for (int nt = 0; nt < 8; ++nt)
                acc1[nt] = mfma16(a, *(const ushort8*)(Ffrag + ((kt * 8 + nt) * 64 + lane) * 8),
                                  acc1[nt]);
        }

        // epilogue: relu*scale, ksum, phi^T -> A-frag layout in PA[s&1]
        {
            const int qc = qa, cc = ra;
            const int kt2 = w >> 1;
            const int qa2 = (w & 1) * 2 + (qc >> 1);
            const int jb  = (qc & 1) * 4;
            ushort_t* PB = PA[s & 1];
#pragma unroll
            for (int nt = 0; nt < 8; ++nt) {
                float4v p = acc1[nt];
                p.x = fmaxf(p.x, 0.f) * PHI_SCALE;
                p.y = fmaxf(p.y, 0.f) * PHI_SCALE;
                p.z = fmaxf(p.z, 0.f) * PHI_SCALE;
                p.w = fmaxf(p.w, 0.f) * PHI_SCALE;
                ksum_acc[nt] += p.x + p.y + p.z + p.w;
                ushort4v u4 = {f2bf(p.x), f2bf(p.y), f2bf(p.z), f2bf(p.w)};
                *(ushort4v*)(PB + (((kt2 * 8 + nt) * 64 + qa2 * 16 + cc) * 8 + jb)) = u4;
            }
        }
        __syncthreads();

        // GEMM2: kv[m][v] += phi^T (128m x 64l) @ V^T (64l x 128v); wave w: v in [32w, 32w+32)
        const ushort_t* PB = PA[s & 1];
        const int qb = qa, cb = ra;
#pragma unroll
        for (int kt2 = 0; kt2 < 2; ++kt2) {
            ushort8 bfrag[2];
#pragma unroll
            for (int vt = 0; vt < 2; ++vt) {
                const float* vp = values + ((size_t)(b * D_ + w * 32 + vt * 16 + cb)) * L_
                                + ls + kt2 * 32 + qb * 8;
                float4v f0 = *(const float4v*)vp;
                float4v f1 = *(const float4v*)(vp + 4);
                ushort8 u;
                u[0] = f2bf(f0.x); u[1] = f2bf(f0.y); u[2] = f2bf(f0.z); u[3] = f2bf(f0.w);
                u[4] = f2bf(f1.x); u[5] = f2bf(f1.y); u[6] = f2bf(f1.z); u[7] = f2bf(f1.w);
                bfrag[vt] = u;
            }
#pragma unroll
            for (int mt = 0; mt < 8; ++mt) {
                ushort8 af = *(const ushort8*)(PB + ((kt2 * 8 + mt) * 64 + lane) * 8);
                acc2[mt][0] = mfma16(af, bfrag[0], acc2[mt][0]);
                acc2[mt][1] = mfma16(af, bfrag[1], acc2[mt][1]);
            }
        }
    }

    // write kv partials: wave w owns v cols [32w, 32w+32)
    float* kvpb = kvp + ((size_t)(b * NCA + chunk)) * M_ * D_;
    const int qc = lane >> 4, cc = lane & 15;
#pragma unroll
    for (int mt = 0; mt < 8; ++mt)
#pragma unroll
        for (int vt = 0; vt < 2; ++vt) {
            float4v p = acc2[mt][vt];
            int m0 = mt * 16 + qc * 4;
            int v  = w * 32 + vt * 16 + cc;
            kvpb[(m0 + 0) * D_ + v] = p.x;
            kvpb[(m0 + 1) * D_ + v] = p.y;
            kvpb[(m0 + 2) * D_ + v] = p.z;
            kvpb[(m0 + 3) * D_ + v] = p.w;
        }
    float* ksb = ksum_p + ((size_t)((b * NCA + chunk) * 4 + w)) * M_;
#pragma unroll
    for (int nt = 0; nt < 8; ++nt) {
        float sv = ksum_acc[nt];
        sv += __shfl_xor(sv, 16);
        sv += __shfl_xor(sv, 32);
        if (qc == 0) ksb[nt * 16 + cc] = sv;
    }
}

// ---- kernelR: reduce NCA chunk-partials -> kv_ext (128 x 144, tile 8 = ksum col) bf16
// B-frag layout blocks [kt 0..3][nt 0..8][lane64][j]; one thread per 16B slot.
__global__ __launch_bounds__(256) void kernelR(const float* __restrict__ kvp,
                                               const float* __restrict__ ksum_p,
                                               ushort_t* __restrict__ kv_final) {
    int t = blockIdx.x * 256 + threadIdx.x;  // 0..36863
    int b = t / 2304, bid = t % 2304;
    int cb = bid & 15, qb = (bid >> 4) & 3, rest = bid >> 6;
    int nt = rest % 9, kt = rest / 9;
    ushort8 u = {0, 0, 0, 0, 0, 0, 0, 0};
    if (nt < 8) {
        int v = nt * 16 + cb;
#pragma unroll
        for (int j = 0; j < 8; ++j) {
            int m = kt * 32 + qb * 8 + j;
            float sum = 0.f;
        for (int c = 0; c < NCA; ++c)
                sum += kvp[(((size_t)b * NCA + c) * M_ + m) * D_ + v];
            u[j] = f2bf(sum);
        }
    } else if (cb == 0) {  // col 128 = ksum
#pragma unroll
        for (int j = 0; j < 8; ++j) {
            int m = kt * 32 + qb * 8 + j;
            float sum = 0.f;
            for (int c = 0; c < NCA; ++c)
#pragma unroll
                for (int w2 = 0; w2 < 4; ++w2)
                    sum += ksum_p[((size_t)((b * NCA + c) * 4 + w2)) * M_ + m];
            u[j] = f2bf(sum);
        }
    }
    *(ushort8*)(kv_final + (size_t)t * 8) = u;
}

// ---- kernelC: fused phi_q + out. kv_ext staged ONCE in LDS; phi via wave-private
// LDS scatter (no barrier); denom via 9th n-tile; float4 stores along L.
__global__ __launch_bounds__(256) void kernelC(const float* __restrict__ queries,
                                               const ushort_t* __restrict__ Ffrag,
                                               const ushort_t* __restrict__ kv_final,
                                               float* __restrict__ out) {
    __shared__ ushort_t KVB[18432];  // 36 KB kv_ext B-frags
    __shared__ ushort_t PA[8192];    // 16 KB phi_q A-frags, 4 KB per wave

    const int tid = threadIdx.x;
    const int chunk = blockIdx.x, b = blockIdx.y;
#pragma unroll
    for (int it = 0; it < 9; ++it) {
        int bid = tid + it * 256;  // 0..2303
        *(ushort8*)(KVB + bid * 8) =
            *(const ushort8*)(kv_final + ((size_t)b * 2304 + bid) * 8);
    }
    __syncthreads();

    const int w = tid >> 6, lane = tid & 63;
    const int qa = lane >> 4, ra = lane & 15;

    for (int s = 0; s < LTC / SL; ++s) {
        const int ls = chunk * LTC + s * SL;
        const int l = ls + w * 16 + ra;

        // GEMM1: phi(64l x 128m) = Q_sub^T @ F
        float4v acc1[8];
#pragma unroll
        for (int nt = 0; nt < 8; ++nt) acc1[nt] = (float4v){0.f, 0.f, 0.f, 0.f};
#pragma unroll
        for (int kt = 0; kt < 4; ++kt) {
            const float* qp = queries + ((size_t)(b * D_ + kt * 32 + qa * 8)) * L_ + l;
            ushort8 a;
#pragma unroll
            for (int j = 0; j < 8; ++j) a[j] = f2bf(qp[(size_t)j * L_]);
#pragma unroll
            for (int nt = 0; nt < 8; ++nt)
                acc1[nt] = mfma16(a, *(const ushort8*)(Ffrag + ((kt * 8 + nt) * 64 + lane) * 8),
                                  acc1[nt]);
        }

        // scatter phi into wave-private A-frag region of PA (r2-verified mapping)
        const int qc = qa, cc = ra;
#pragma unroll
        for (int nt = 0; nt < 8; ++nt) {
            float4v p = acc1[nt];
            p.x = fmaxf(p.x, 0.f) * PHI_SCALE;
            p.y = fmaxf(p.y, 0.f) * PHI_SCALE;
            p.z = fmaxf(p.z, 0.f) * PHI_SCALE;
            p.w = fmaxf(p.w, 0.f) * PHI_SCALE;
            int ktile = nt >> 1;
            int qb2 = (nt & 1) * 2 + (cc >> 3);
            ushort_t* pp = PA + (((ktile * 4 + w) * 64 + qb2 * 16 + qc * 4) * 8 + (cc & 7));
            pp[0]  = f2bf(p.x);
            pp[8]  = f2bf(p.y);
            pp[16] = f2bf(p.z);
            pp[24] = f2bf(p.w);
        }

        // GEMM2: out(64l x 144) = phi_q @ kv_ext ; 9th tile col 0 = denom
        float4v acc[9];
#pragma unroll
        for (int nt = 0; nt < 9; ++nt) acc[nt] = (float4v){0.f, 0.f, 0.f, 0.f};
#pragma unroll
        for (int kt = 0; kt < 4; ++kt) {
            ushort8 a = *(const ushort8*)(PA + ((kt * 4 + w) * 64 + lane) * 8);
#pragma unroll
            for (int nt = 0; nt < 9; ++nt)
                acc[nt] = mfma16(a, *(const ushort8*)(KVB + ((kt * 9 + nt) * 64 + lane) * 8),
                                 acc[nt]);
        }

        float4v dv = acc[8];
        int src = lane & 48;
        float i0 = 1.0f / __shfl(dv.x, src);
        float i1 = 1.0f / __shfl(dv.y, src);
        float i2 = 1.0f / __shfl(dv.z, src);
        float i3 = 1.0f / __shfl(dv.w, src);
        const int lbase = ls + w * 16 + qa * 4;
#pragma unroll
        for (int nt = 0; nt < 8; ++nt) {
            float4v o = acc[nt];
            o.x *= i0; o.y *= i1; o.z *= i2; o.w *= i3;
            *(float4v*)(out + ((size_t)(b * D_ + nt * 16 + ra)) * L_ + lbase) = o;
        }
    }
}

extern "C" void kernel_launch(void* const* d_in, const int* in_sizes, int n_in,
                              void* d_out, int out_size, void* d_ws, size_t ws_size,
                              hipStream_t stream) {
    (void)in_sizes; (void)n_in; (void)out_size; (void)ws_size;
    const float* keys     = (const float*)d_in[0];
    const float* values   = (const float*)d_in[1];
    const float* queries  = (const float*)d_in[2];
    const float* features = (const float*)d_in[3];
    float* out = (float*)d_out;

    // workspace partition (~35.2 MB)
    char* ws = (char*)d_ws;
    float*    kvp      = (float*)ws;                               // 16*32*128*128*4 = 33,554,432
    float*    ksum_p   = (float*)(ws + 33554432);                  // 16*32*4*128*4   =  1,048,576
    ushort_t* Ffrag    = (ushort_t*)(ws + 33554432 + 1048576);     // 2048*8*2        =     32,768
    ushort_t* kv_final = (ushort_t*)(ws + 33554432 + 1048576 + 32768);  // 16*2304*8*2 = 589,824

    kernelF<<<8, 256, 0, stream>>>(features, Ffrag);
    kernelA<<<dim3(NCA, B_), 256, 0, stream>>>(keys, values, Ffrag, kvp, ksum_p);
    kernelR<<<144, 256, 0, stream>>>(kvp, ksum_p, kv_final);
    kernelC<<<dim3(NCC, B_), 256, 0, stream>>>(queries, Ffrag, kv_final, out);
}